// Round 4
// baseline (322.241 us; speedup 1.0000x reference)
//
#include <hip/hip_runtime.h>
#include <cstdint>
#include <cstddef>

#define NPTS 4096
#define KNN  16
#define INV_DEG (1.0f / 17.0f)
#define CAP  48    // knn per-point candidate buffer
#define TS   1024  // candidate coord tile size (12 KB LDS)

typedef unsigned long long u64;
typedef unsigned int u32;
typedef float v2f __attribute__((ext_vector_type(2)));

__device__ __forceinline__ u32 mapmono(float f) {
  u32 u = __float_as_uint(f);
  return u ^ ((u32)((int)u >> 31) | 0x80000000u);
}
__device__ __forceinline__ float unmapmono(u32 m) {
  u32 u = (m & 0x80000000u) ? (m ^ 0x80000000u) : ~m;
  return __uint_as_float(u);
}
__device__ __forceinline__ u64 u64min(u64 a, u64 b) { return a < b ? a : b; }
__device__ __forceinline__ u64 u64max(u64 a, u64 b) { return a > b ? a : b; }

// Full 64-lane bitonic sort, ascending by lane (verified R1-R3).
__device__ __forceinline__ u64 bitonic64(u64 key, int lane) {
#pragma unroll
  for (int k = 2; k <= 64; k <<= 1) {
#pragma unroll
    for (int m = k >> 1; m >= 1; m >>= 1) {
      u64 partner = __shfl_xor(key, m, 64);
      bool up = ((lane & k) == 0);
      bool lower = ((lane & m) == 0);
      u64 mn = u64min(key, partner);
      u64 mx = u64max(key, partner);
      key = (lower == up) ? mn : mx;
    }
  }
  return key;
}

// ---------------------------------------------------------------------------
// K1: exact KNN. NOTE: plain __launch_bounds__(512) — the (512,6) min-waves
// hint in R3 forced VGPR=40 + ~45MB scratch spill traffic (WRITE_SIZE 35MB)
// and cost 80us. 24KB LDS already allows the wave-capped 4 blocks/CU.
// ---------------------------------------------------------------------------
__global__ __launch_bounds__(512) void knn_kernel(const float* __restrict__ feats,
                                                  int* __restrict__ nbr) {
#pragma clang fp contract(off)
  __shared__ float sx[TS], sy[TS], sz[TS];  // 12 KB
  __shared__ u64 sbuf[8][4][CAP];           // 12 KB

  const int b = blockIdx.x >> 6;
  const int pbase = (blockIdx.x & 63) * 64;
  const float* fb = feats + (size_t)b * NPTS * 6;
  const int wave = threadIdx.x >> 6;
  const int lane = threadIdx.x & 63;

  for (int g = 0; g < 2; ++g) {
    int ip[4];
    float xi[4], yi[4], zi[4], sqi[4], tau[4];
    u64 slot[4];
    int cnt[4];
#pragma unroll
    for (int p = 0; p < 4; ++p) {
      ip[p] = pbase + wave * 8 + g * 4 + p;
      const float* fr = fb + (size_t)ip[p] * 6;
      xi[p] = fr[0]; yi[p] = fr[1]; zi[p] = fr[2];
      sqi[p] = __fadd_rn(__fadd_rn(__fmul_rn(xi[p], xi[p]), __fmul_rn(yi[p], yi[p])),
                         __fmul_rn(zi[p], zi[p]));
      tau[p] = __uint_as_float(0x7f800000u);
      slot[p] = ~0ull;
      cnt[p] = 0;
    }

    auto flush = [&](int p, bool fin) {
      u64 key;
      if (lane < 16) {
        key = slot[p];
      } else {
        const int idx = lane - 16;
        key = (idx < cnt[p]) ? sbuf[wave][p][idx] : ~0ull;
      }
      if ((u32)key == (u32)ip[p]) key = ~0ull;  // neutralize self
      key = bitonic64(key, lane);
      if (fin) {
        if (lane < KNN)
          nbr[((size_t)(b * NPTS) + ip[p]) * KNN + lane] = (int)(u32)key;
      } else {
        if (lane < 16) slot[p] = key;
        tau[p] = unmapmono((u32)(__shfl(key, 15, 64) >> 32));
      }
      cnt[p] = 0;
    };

    for (int tb = 0; tb < NPTS; tb += TS) {
      __syncthreads();  // prev tile readers done
      for (int t = threadIdx.x; t < TS; t += 512) {
        const float* fr = fb + (size_t)(tb + t) * 6;
        sx[t] = fr[0]; sy[t] = fr[1]; sz[t] = fr[2];
      }
      __syncthreads();

      for (int jb0 = 0; jb0 < TS; jb0 += 64) {
        const int tl = jb0 + lane;
        const int j = tb + tl;
        const float cx = sx[tl], cy = sy[tl], cz = sz[tl];
        const float sqj = __fadd_rn(__fadd_rn(__fmul_rn(cx, cx), __fmul_rn(cy, cy)),
                                    __fmul_rn(cz, cz));
        if (tb == 0 && jb0 == 0) {
#pragma unroll
          for (int p = 0; p < 4; ++p) {
            float dot = __fmul_rn(xi[p], cx);
            dot = __fmaf_rn(yi[p], cy, dot);
            dot = __fmaf_rn(zi[p], cz, dot);
            const float d2 = __fsub_rn(__fadd_rn(sqi[p], sqj), __fmul_rn(2.0f, dot));
            u64 key = ((u64)mapmono(d2) << 32) | (u32)j;
            if (j == ip[p]) key = ~0ull;
            key = bitonic64(key, lane);
            if (lane < 16) slot[p] = key;
            tau[p] = unmapmono((u32)(__shfl(key, 15, 64) >> 32));
          }
          continue;
        }

        const v2f cx2 = {cx, cx}, cy2 = {cy, cy}, cz2 = {cz, cz}, sq2 = {sqj, sqj};
        float d2s[4];
#pragma unroll
        for (int pp = 0; pp < 2; ++pp) {
          v2f X = {xi[2 * pp], xi[2 * pp + 1]};
          v2f Y = {yi[2 * pp], yi[2 * pp + 1]};
          v2f Z = {zi[2 * pp], zi[2 * pp + 1]};
          v2f SQ = {sqi[2 * pp], sqi[2 * pp + 1]};
          v2f dot = X * cx2;
          dot = __builtin_elementwise_fma(Y, cy2, dot);
          dot = __builtin_elementwise_fma(Z, cz2, dot);
          v2f two = {2.0f, 2.0f};
          v2f d2 = (SQ + sq2) - two * dot;  // contract(off): rn each op
          d2s[2 * pp] = d2.x;
          d2s[2 * pp + 1] = d2.y;
        }
#pragma unroll
        for (int p = 0; p < 4; ++p) {
          const bool pred = d2s[p] <= tau[p];
          const u64 bal = __ballot(pred);
          if (bal) {
            const int npass = __popcll(bal);
            if (cnt[p] + npass > CAP) flush(p, false);
            const int pos = cnt[p] + (int)__builtin_amdgcn_mbcnt_hi(
                                          (u32)(bal >> 32),
                                          __builtin_amdgcn_mbcnt_lo((u32)bal, 0));
            const u64 key = ((u64)mapmono(d2s[p]) << 32) | (u32)j;
            if (npass <= CAP) {
              if (pred) sbuf[wave][p][pos] = key;
              cnt[p] += npass;
            } else {  // pathological: npass in (48,64]
              if (pred && pos < CAP) sbuf[wave][p][pos] = key;
              cnt[p] = CAP;
              flush(p, false);
              if (pred && pos >= CAP) sbuf[wave][p][pos - CAP] = key;
              cnt[p] = npass - CAP;
            }
          }
        }
      }
    }
#pragma unroll
    for (int p = 0; p < 4; ++p) flush(p, true);
  }
}

// ---------------------------------------------------------------------------
// T1: x1 = relu(((feats + sum_nbr feats) @ W1) * inv_deg + b1).  64 pts/block.
// ---------------------------------------------------------------------------
__global__ __launch_bounds__(256) void enc1_kernel(const float* __restrict__ feats,
                                                   const int* __restrict__ nbr,
                                                   const float* __restrict__ W1,
                                                   const float* __restrict__ b1,
                                                   float* __restrict__ x1) {
  __shared__ float af[64][6];
  const int tid = threadIdx.x;
  const int n0 = blockIdx.x * 64;
  const int gb = n0 & ~(NPTS - 1);

  if (tid < 128) {
    const int p = tid >> 1, h = tid & 1;
    const int n = n0 + p;
    const int d0 = h * 3;
    const int* nb = nbr + (size_t)n * KNN;
    const float* fr = feats + (size_t)n * 6 + d0;
    float a0 = fr[0], a1 = fr[1], a2 = fr[2];
#pragma unroll
    for (int t = 0; t < KNN; ++t) {
      const float* fq = feats + (size_t)(gb + nb[t]) * 6 + d0;
      a0 += fq[0]; a1 += fq[1]; a2 += fq[2];
    }
    af[p][d0] = a0; af[p][d0 + 1] = a1; af[p][d0 + 2] = a2;
  }
  __syncthreads();

  const int c = tid & 63, pg = tid >> 6;
  float w[6];
#pragma unroll
  for (int k = 0; k < 6; ++k) w[k] = W1[k * 64 + c];
  const float bv = b1[c];
  for (int pi = 0; pi < 16; ++pi) {
    const int p = pg * 16 + pi;
    float s = 0.f;
#pragma unroll
    for (int k = 0; k < 6; ++k) s = fmaf(af[p][k], w[k], s);
    x1[(size_t)(n0 + p) * 64 + c] = fmaxf(fmaf(s, INV_DEG, bv), 0.f);
  }
}

// ---------------------------------------------------------------------------
// T2: x2 = relu(((x1 + sum_nbr x1) @ W2) * inv_deg + b2).  64 pts/block.
// W2 in registers (v2f w[64]: channels lane & lane+64); activations broadcast
// from 16KB LDS tile (uniform-address reads = conflict-free broadcast).
// ---------------------------------------------------------------------------
__global__ __launch_bounds__(256) void enc2_kernel(const float* __restrict__ x1,
                                                   const int* __restrict__ nbr,
                                                   const float* __restrict__ W2,
                                                   const float* __restrict__ b2,
                                                   float* __restrict__ x2) {
  __shared__ float a1s[64][64];  // 16 KB
  const int tid = threadIdx.x;
  const int n0 = blockIdx.x * 64;
  const int gb = n0 & ~(NPTS - 1);
  const int wave = tid >> 6, lane = tid & 63;

  // weights -> registers (coalesced, L2-hot; independent of gather)
  v2f w[64];
#pragma unroll
  for (int k = 0; k < 64; ++k) {
    w[k].x = W2[k * 128 + lane];
    w[k].y = W2[k * 128 + 64 + lane];
  }

  // gather + aggregate 64 points (16 threads/point, float4 channels)
#pragma unroll
  for (int r = 0; r < 4; ++r) {
    const int p = r * 16 + (tid >> 4), c4 = tid & 15;
    const int n = n0 + p;
    const int* nb = nbr + (size_t)n * KNN;
    float4 s = ((const float4*)(x1 + (size_t)n * 64))[c4];
#pragma unroll
    for (int t = 0; t < KNN; ++t) {
      float4 v = ((const float4*)(x1 + (size_t)(gb + nb[t]) * 64))[c4];
      s.x += v.x; s.y += v.y; s.z += v.z; s.w += v.w;
    }
    *((float4*)&a1s[p][c4 * 4]) = s;
  }
  __syncthreads();

  const float bx = b2[lane], by = b2[lane + 64];
#pragma unroll
  for (int g = 0; g < 4; ++g) {
    const int p0 = wave * 16 + g * 4;
    v2f acc0 = {0, 0}, acc1 = {0, 0}, acc2 = {0, 0}, acc3 = {0, 0};
    for (int k = 0; k < 64; k += 4) {
      const float4 a0 = *(const float4*)&a1s[p0 + 0][k];
      const float4 a1v = *(const float4*)&a1s[p0 + 1][k];
      const float4 a2v = *(const float4*)&a1s[p0 + 2][k];
      const float4 a3v = *(const float4*)&a1s[p0 + 3][k];
#pragma unroll
      for (int kk = 0; kk < 4; ++kk) {
        const v2f wv = w[k + kk];
        const float e0 = kk == 0 ? a0.x : kk == 1 ? a0.y : kk == 2 ? a0.z : a0.w;
        const float e1 = kk == 0 ? a1v.x : kk == 1 ? a1v.y : kk == 2 ? a1v.z : a1v.w;
        const float e2 = kk == 0 ? a2v.x : kk == 1 ? a2v.y : kk == 2 ? a2v.z : a2v.w;
        const float e3 = kk == 0 ? a3v.x : kk == 1 ? a3v.y : kk == 2 ? a3v.z : a3v.w;
        v2f v0 = {e0, e0}, v1 = {e1, e1}, v2 = {e2, e2}, v3 = {e3, e3};
        acc0 = __builtin_elementwise_fma(v0, wv, acc0);
        acc1 = __builtin_elementwise_fma(v1, wv, acc1);
        acc2 = __builtin_elementwise_fma(v2, wv, acc2);
        acc3 = __builtin_elementwise_fma(v3, wv, acc3);
      }
    }
    v2f accs[4] = {acc0, acc1, acc2, acc3};
#pragma unroll
    for (int pi = 0; pi < 4; ++pi) {
      float* row = x2 + (size_t)(n0 + p0 + pi) * 128;
      row[lane] = fmaxf(fmaf(accs[pi].x, INV_DEG, bx), 0.f);
      row[lane + 64] = fmaxf(fmaf(accs[pi].y, INV_DEG, by), 0.f);
    }
  }
}

// ---------------------------------------------------------------------------
// T3: out = x2 @ Wf + bf (K=128). Lane owns ONE output channel, full K in
// 128 VGPRs; x2 rows broadcast from LDS. No split-K, no part buffer.
// In-place safe on d_out: block stages all its rows before any store.
// ---------------------------------------------------------------------------
__global__ __launch_bounds__(256) void enc3_kernel(const float* __restrict__ x2,
                                                   const float* __restrict__ Wf,
                                                   const float* __restrict__ bf,
                                                   float* __restrict__ out) {
  __shared__ float xs[64][128];  // 32 KB
  const int tid = threadIdx.x;
  const int n0 = blockIdx.x * 64;
  const int wave = tid >> 6, lane = tid & 63;
  const int ch = wave & 1, pg = wave >> 1;  // ch-half, point-group
  const int c = ch * 64 + lane;

  float w[128];
#pragma unroll
  for (int j = 0; j < 128; ++j) w[j] = Wf[j * 128 + c];
  const float bv = bf[c];

#pragma unroll
  for (int i = 0; i < 8; ++i) {
    const int e = tid + 256 * i;  // 2048 float4 = 64 rows x 128
    ((float4*)xs)[e] = ((const float4*)(x2 + (size_t)n0 * 128))[e];
  }
  __syncthreads();

  for (int pi = 0; pi < 32; ++pi) {
    const int p = pg * 32 + pi;
    float acc = 0.f;
    for (int j = 0; j < 128; j += 4) {
      const float4 a = *(const float4*)&xs[p][j];
      acc = fmaf(a.x, w[j + 0], acc);
      acc = fmaf(a.y, w[j + 1], acc);
      acc = fmaf(a.z, w[j + 2], acc);
      acc = fmaf(a.w, w[j + 3], acc);
    }
    out[(size_t)(n0 + p) * 128 + c] = acc + bv;
  }
}

// ---------------------------------------------------------------------------
// Workspace: nbr@0 (2MB), x1@2MB (8MB). x2 lives in d_out (enc3 in-place).
// ---------------------------------------------------------------------------
extern "C" void kernel_launch(void* const* d_in, const int* in_sizes, int n_in,
                              void* d_out, int out_size, void* d_ws, size_t ws_size,
                              hipStream_t stream) {
  const float* feats = (const float*)d_in[0];
  const float* W1 = (const float*)d_in[1];
  const float* b1 = (const float*)d_in[2];
  const float* W2 = (const float*)d_in[3];
  const float* b2 = (const float*)d_in[4];
  const float* Wf = (const float*)d_in[5];
  const float* bf = (const float*)d_in[6];
  float* out = (float*)d_out;

  char* ws = (char*)d_ws;
  int* nbr = (int*)ws;
  float* x1 = (float*)(ws + (size_t)(2 << 20));
  float* x2 = out;

  knn_kernel<<<512, 512, 0, stream>>>(feats, nbr);
  enc1_kernel<<<512, 256, 0, stream>>>(feats, nbr, W1, b1, x1);
  enc2_kernel<<<512, 256, 0, stream>>>(x1, nbr, W2, b2, x2);
  enc3_kernel<<<512, 256, 0, stream>>>(x2, Wf, bf, out);
}

// Round 5
// 247.219 us; speedup vs baseline: 1.3035x; 1.3035x over previous
//
#include <hip/hip_runtime.h>
#include <cstdint>
#include <cstddef>

#define NPTS 4096
#define KNN  16
#define INV_DEG (1.0f / 17.0f)
#define CAP  48    // knn per-point candidate buffer (entries [48..64) = slot staging)
#define TS   1024  // candidate coord tile (12 KB LDS)

typedef unsigned long long u64;
typedef unsigned int u32;
typedef float v2f __attribute__((ext_vector_type(2)));

__device__ __forceinline__ u32 mapmono(float f) {
  u32 u = __float_as_uint(f);
  return u ^ ((u32)((int)u >> 31) | 0x80000000u);
}
__device__ __forceinline__ float unmapmono(u32 m) {
  u32 u = (m & 0x80000000u) ? (m ^ 0x80000000u) : ~m;
  return __uint_as_float(u);
}

// ---------------------------------------------------------------------------
// K1: exact KNN (top-16 smallest d2, tie -> lower index).
// Lessons baked in: (R3) never pass a min-waves hint here — VGPR squeeze
// spills ~45MB to scratch; (R4) flush must be the LDS rank-select (pipelined,
// throughput-bound), NOT a shfl bitonic (21 dependent bpermutes = latency
// chain). Grid 1024 x 512 (32 pts/block) -> 4 blocks/CU co-resident (28 KB
// LDS), targeting 32 waves/CU vs R2/R4's grid-limited 16.
// ---------------------------------------------------------------------------
__global__ __launch_bounds__(512) void knn_kernel(const float* __restrict__ feats,
                                                  int* __restrict__ nbr) {
#pragma clang fp contract(off)
  __shared__ float sx[TS], sy[TS], sz[TS];  // 12 KB
  __shared__ u64 sbuf[8][4][64];            // 16 KB

  const int b = blockIdx.x >> 7;
  const int pbase = (blockIdx.x & 127) * 32;
  const float* fb = feats + (size_t)b * NPTS * 6;
  const int wave = threadIdx.x >> 6;
  const int lane = threadIdx.x & 63;

  int ip[4];
  float xi[4], yi[4], zi[4], sqi[4], tau[4];
  u64 slot[4];
  int cnt[4];
#pragma unroll
  for (int p = 0; p < 4; ++p) {
    ip[p] = pbase + wave * 4 + p;
    const float* fr = fb + (size_t)ip[p] * 6;
    xi[p] = fr[0]; yi[p] = fr[1]; zi[p] = fr[2];
    sqi[p] = __fadd_rn(__fadd_rn(__fmul_rn(xi[p], xi[p]), __fmul_rn(yi[p], yi[p])),
                       __fmul_rn(zi[p], zi[p]));
    tau[p] = __uint_as_float(0x7f800000u);  // +inf: batch 0 all-pass bootstraps
    slot[p] = ~0ull;
    cnt[p] = 0;
  }

  // LDS rank-select merge of {<=48 buffered} U {16 slots} (verified R1/R2).
  auto flush = [&](int p, bool fin) {
    u64* wb = &sbuf[wave][p][0];
    if (lane >= cnt[p] && lane < CAP) wb[lane] = ~0ull;  // clear unused
    if (lane < KNN) wb[CAP + lane] = slot[p];            // stage slots
    u64 myk = wb[lane];
    if ((u32)myk == (u32)ip[p]) {  // neutralize self
      myk = ~0ull;
      wb[lane] = ~0ull;
    }
    int rank = 0;
#pragma unroll
    for (int m = 0; m < 64; m += 4) {
      u64 k0 = wb[m], k1 = wb[m + 1], k2 = wb[m + 2], k3 = wb[m + 3];
      rank += (int)(k0 < myk) + (int)(k1 < myk) + (int)(k2 < myk) + (int)(k3 < myk);
    }
    if (fin) {
      if (rank < KNN)
        nbr[((size_t)(b * NPTS) + ip[p]) * KNN + rank] = (int)(u32)myk;
    } else {
      if (rank < KNN) wb[rank] = myk;
      u64 s15 = wb[15];
      if (lane < KNN) slot[p] = wb[lane];
      tau[p] = unmapmono((u32)(s15 >> 32));
    }
    cnt[p] = 0;
  };

  for (int tb = 0; tb < NPTS; tb += TS) {
    __syncthreads();  // prev tile readers done
    for (int t = threadIdx.x; t < TS; t += 512) {
      const float* fr = fb + (size_t)(tb + t) * 6;
      sx[t] = fr[0]; sy[t] = fr[1]; sz[t] = fr[2];
    }
    __syncthreads();

    for (int jb0 = 0; jb0 < TS; jb0 += 64) {
      const int tl = jb0 + lane;
      const int j = tb + tl;
      const float cx = sx[tl], cy = sy[tl], cz = sz[tl];
      const float sqj = __fadd_rn(__fadd_rn(__fmul_rn(cx, cx), __fmul_rn(cy, cy)),
                                  __fmul_rn(cz, cz));
      const v2f cx2 = {cx, cx}, cy2 = {cy, cy}, cz2 = {cz, cz}, sq2 = {sqj, sqj};
      float d2s[4];
#pragma unroll
      for (int pp = 0; pp < 2; ++pp) {
        v2f X = {xi[2 * pp], xi[2 * pp + 1]};
        v2f Y = {yi[2 * pp], yi[2 * pp + 1]};
        v2f Z = {zi[2 * pp], zi[2 * pp + 1]};
        v2f SQ = {sqi[2 * pp], sqi[2 * pp + 1]};
        v2f dot = X * cx2;
        dot = __builtin_elementwise_fma(Y, cy2, dot);
        dot = __builtin_elementwise_fma(Z, cz2, dot);
        v2f two = {2.0f, 2.0f};
        v2f d2 = (SQ + sq2) - two * dot;  // contract(off): rn each op
        d2s[2 * pp] = d2.x;
        d2s[2 * pp + 1] = d2.y;
      }
#pragma unroll
      for (int p = 0; p < 4; ++p) {
        const bool pred = d2s[p] <= tau[p];
        const u64 bal = __ballot(pred);
        if (bal) {
          const int npass = __popcll(bal);
          if (cnt[p] + npass > CAP) flush(p, false);
          const int pos = cnt[p] + (int)__builtin_amdgcn_mbcnt_hi(
                                        (u32)(bal >> 32),
                                        __builtin_amdgcn_mbcnt_lo((u32)bal, 0));
          const u64 key = ((u64)mapmono(d2s[p]) << 32) | (u32)j;
          if (npass <= CAP) {
            if (pred) sbuf[wave][p][pos] = key;
            cnt[p] += npass;
          } else {  // npass in (48,64]: batch 0 bootstrap + pathological ties
            if (pred && pos < CAP) sbuf[wave][p][pos] = key;
            cnt[p] = CAP;
            flush(p, false);
            if (pred && pos >= CAP) sbuf[wave][p][pos - CAP] = key;
            cnt[p] = npass - CAP;
          }
        }
      }
    }
  }
#pragma unroll
  for (int p = 0; p < 4; ++p) flush(p, true);
}

// ---------------------------------------------------------------------------
// T1: x1 = relu(((feats + sum_nbr feats) @ W1) * inv_deg + b1).  64 pts/block.
// (R3 tail verbatim — measured 95.8 us total; R4's reg-weight variants = 144.)
// ---------------------------------------------------------------------------
__global__ __launch_bounds__(256) void enc1_kernel(const float* __restrict__ feats,
                                                   const int* __restrict__ nbr,
                                                   const float* __restrict__ W1,
                                                   const float* __restrict__ b1,
                                                   float* __restrict__ x1) {
  __shared__ float af[64][6];
  const int tid = threadIdx.x;
  const int n0 = blockIdx.x * 64;
  const int gb = n0 & ~(NPTS - 1);

  if (tid < 128) {
    const int p = tid >> 1, h = tid & 1;
    const int n = n0 + p;
    const int d0 = h * 3;
    const int* nb = nbr + (size_t)n * KNN;
    const float* fr = feats + (size_t)n * 6 + d0;
    float a0 = fr[0], a1 = fr[1], a2 = fr[2];
#pragma unroll
    for (int t = 0; t < KNN; ++t) {
      const float* fq = feats + (size_t)(gb + nb[t]) * 6 + d0;
      a0 += fq[0]; a1 += fq[1]; a2 += fq[2];
    }
    af[p][d0] = a0; af[p][d0 + 1] = a1; af[p][d0 + 2] = a2;
  }
  __syncthreads();

  const int c = tid & 63, pg = tid >> 6;
  float w[6];
#pragma unroll
  for (int k = 0; k < 6; ++k) w[k] = W1[k * 64 + c];
  const float bv = b1[c];
  for (int pi = 0; pi < 16; ++pi) {
    const int p = pg * 16 + pi;
    float s = 0.f;
#pragma unroll
    for (int k = 0; k < 6; ++k) s = fmaf(af[p][k], w[k], s);
    x1[(size_t)(n0 + p) * 64 + c] = fmaxf(fmaf(s, INV_DEG, bv), 0.f);
  }
}

// ---------------------------------------------------------------------------
// T2: x2 = relu(((x1 + sum_nbr x1) @ W2) * inv_deg + b2).  16 pts/block.
// W2 staged paired in LDS (R3 verbatim).
// ---------------------------------------------------------------------------
__global__ __launch_bounds__(256) void enc2_kernel(const float* __restrict__ x1,
                                                   const int* __restrict__ nbr,
                                                   const float* __restrict__ W2,
                                                   const float* __restrict__ b2,
                                                   float* __restrict__ x2) {
  __shared__ float a1s[16][64];  // 4 KB
  __shared__ v2f w2s[64][64];    // 32 KB
  const int tid = threadIdx.x;
  const int n0 = blockIdx.x * 16;
  const int gb = n0 & ~(NPTS - 1);

#pragma unroll
  for (int i = 0; i < 16; ++i) {
    const int e = tid + 256 * i;
    const int k = e >> 6, l = e & 63;
    v2f w;
    w.x = W2[k * 128 + l];
    w.y = W2[k * 128 + 64 + l];
    w2s[k][l] = w;
  }
  {
    const int p = tid >> 4, c4 = tid & 15;
    const int n = n0 + p;
    const int* nb = nbr + (size_t)n * KNN;
    float4 s = ((const float4*)(x1 + (size_t)n * 64))[c4];
#pragma unroll
    for (int t = 0; t < KNN; ++t) {
      float4 v = ((const float4*)(x1 + (size_t)(gb + nb[t]) * 64))[c4];
      s.x += v.x; s.y += v.y; s.z += v.z; s.w += v.w;
    }
    *((float4*)&a1s[p][c4 * 4]) = s;
  }
  __syncthreads();

  const int wave = tid >> 6, lane = tid & 63;
  const int p0 = wave * 4;
  const float bx = b2[lane], by = b2[lane + 64];
  v2f acc0 = {0, 0}, acc1 = {0, 0}, acc2 = {0, 0}, acc3 = {0, 0};
  for (int k = 0; k < 64; k += 4) {
    const float4 a0 = *(const float4*)&a1s[p0 + 0][k];
    const float4 a1v = *(const float4*)&a1s[p0 + 1][k];
    const float4 a2v = *(const float4*)&a1s[p0 + 2][k];
    const float4 a3v = *(const float4*)&a1s[p0 + 3][k];
#pragma unroll
    for (int kk = 0; kk < 4; ++kk) {
      const v2f w = w2s[k + kk][lane];
      const float e0 = kk == 0 ? a0.x : kk == 1 ? a0.y : kk == 2 ? a0.z : a0.w;
      const float e1 = kk == 0 ? a1v.x : kk == 1 ? a1v.y : kk == 2 ? a1v.z : a1v.w;
      const float e2 = kk == 0 ? a2v.x : kk == 1 ? a2v.y : kk == 2 ? a2v.z : a2v.w;
      const float e3 = kk == 0 ? a3v.x : kk == 1 ? a3v.y : kk == 2 ? a3v.z : a3v.w;
      v2f v0 = {e0, e0}, v1 = {e1, e1}, v2 = {e2, e2}, v3 = {e3, e3};
      acc0 = __builtin_elementwise_fma(v0, w, acc0);
      acc1 = __builtin_elementwise_fma(v1, w, acc1);
      acc2 = __builtin_elementwise_fma(v2, w, acc2);
      acc3 = __builtin_elementwise_fma(v3, w, acc3);
    }
  }
  v2f accs[4] = {acc0, acc1, acc2, acc3};
#pragma unroll
  for (int pi = 0; pi < 4; ++pi) {
    float* row = x2 + (size_t)(n0 + p0 + pi) * 128;
    row[lane] = fmaxf(fmaf(accs[pi].x, INV_DEG, bx), 0.f);
    row[lane + 64] = fmaxf(fmaf(accs[pi].y, INV_DEG, by), 0.f);
  }
}

// ---------------------------------------------------------------------------
// T3: out = x2 @ Wf + bf (K=128). Split-K wave pairs, Wf in VGPRs, LDS combine
// (R3 verbatim; in-place safe on d_out).
// ---------------------------------------------------------------------------
__global__ __launch_bounds__(256) void enc3_kernel(const float* __restrict__ x2,
                                                   const float* __restrict__ Wf,
                                                   const float* __restrict__ bf,
                                                   float* __restrict__ out) {
  __shared__ float xs[16 * 128];      // 8 KB
  __shared__ float part[2][16][128];  // 16 KB
  const int tid = threadIdx.x;
  const int n0 = blockIdx.x * 16;

#pragma unroll
  for (int i = 0; i < 2; ++i) {
    const int e = tid + 256 * i;
    ((float4*)xs)[e] = ((const float4*)(x2 + (size_t)n0 * 128))[e];
  }

  const int wave = tid >> 6, lane = tid & 63;
  const int kh = wave & 1, pg = wave >> 1;
  v2f w[64];
#pragma unroll
  for (int j = 0; j < 64; ++j) {
    const int k = kh * 64 + j;
    w[j].x = Wf[k * 128 + lane];
    w[j].y = Wf[k * 128 + 64 + lane];
  }
  __syncthreads();

  for (int pi = 0; pi < 8; ++pi) {
    const int p = pg * 8 + pi;
    v2f acc = {0, 0};
    for (int j = 0; j < 64; j += 4) {
      const float4 a = *(const float4*)&xs[p * 128 + kh * 64 + j];
#pragma unroll
      for (int jj = 0; jj < 4; ++jj) {
        const float e = jj == 0 ? a.x : jj == 1 ? a.y : jj == 2 ? a.z : a.w;
        v2f v = {e, e};
        acc = __builtin_elementwise_fma(v, w[j + jj], acc);
      }
    }
    part[kh][p][lane] = acc.x;
    part[kh][p][lane + 64] = acc.y;
  }
  __syncthreads();

#pragma unroll
  for (int i = 0; i < 8; ++i) {
    const int e = tid + 256 * i;
    const int p = e >> 7, c = e & 127;
    out[(size_t)(n0 + p) * 128 + c] = part[0][p][c] + part[1][p][c] + bf[c];
  }
}

// ---------------------------------------------------------------------------
// Workspace: nbr@0 (2MB), x1@2MB (8MB). x2 lives in d_out (enc3 in-place).
// ---------------------------------------------------------------------------
extern "C" void kernel_launch(void* const* d_in, const int* in_sizes, int n_in,
                              void* d_out, int out_size, void* d_ws, size_t ws_size,
                              hipStream_t stream) {
  const float* feats = (const float*)d_in[0];
  const float* W1 = (const float*)d_in[1];
  const float* b1 = (const float*)d_in[2];
  const float* W2 = (const float*)d_in[3];
  const float* b2 = (const float*)d_in[4];
  const float* Wf = (const float*)d_in[5];
  const float* bf = (const float*)d_in[6];
  float* out = (float*)d_out;

  char* ws = (char*)d_ws;
  int* nbr = (int*)ws;
  float* x1 = (float*)(ws + (size_t)(2 << 20));
  float* x2 = out;

  knn_kernel<<<1024, 512, 0, stream>>>(feats, nbr);
  enc1_kernel<<<512, 256, 0, stream>>>(feats, nbr, W1, b1, x1);
  enc2_kernel<<<2048, 256, 0, stream>>>(x1, nbr, W2, b2, x2);
  enc3_kernel<<<2048, 256, 0, stream>>>(x2, Wf, bf, out);
}

// Round 6
// 233.624 us; speedup vs baseline: 1.3793x; 1.0582x over previous
//
#include <hip/hip_runtime.h>
#include <cstdint>
#include <cstddef>

#define NPTS 4096
#define KNN  16
#define INV_DEG (1.0f / 17.0f)
#define CAP  48   // knn per-point candidate buffer (entries [48..64) = slot staging)
#define TS   512  // candidate tile (float4 x/y/z/sq = 8 KB)

typedef unsigned long long u64;
typedef unsigned int u32;
typedef float v2f __attribute__((ext_vector_type(2)));

__device__ __forceinline__ u32 mapmono(float f) {
  u32 u = __float_as_uint(f);
  return u ^ ((u32)((int)u >> 31) | 0x80000000u);
}
__device__ __forceinline__ float unmapmono(u32 m) {
  u32 u = (m & 0x80000000u) ? (m ^ 0x80000000u) : ~m;
  return __uint_as_float(u);
}

// ---------------------------------------------------------------------------
// K1: exact KNN (top-16 smallest d2, tie -> lower index).
// Ledger: (R3) no min-waves hint -> scratch spill; (R4) flush = LDS
// rank-select, NOT shfl bitonic (serial latency chain); (R5) 28KB blocks
// co-schedule only 2/CU => 16KB/block target for 4/CU residency.
// 2 pts/wave, 16 pts/block, grid 2048. Coords+sq prefused in float4 so the
// scan does ONE ds_read_b128 per candidate instead of 3 b32 + sq VALU.
// ---------------------------------------------------------------------------
__global__ __launch_bounds__(512) void knn_kernel(const float* __restrict__ feats,
                                                  int* __restrict__ nbr) {
#pragma clang fp contract(off)
  __shared__ float4 sc[TS];       // 8 KB: {x, y, z, sq}
  __shared__ u64 sbuf[8][2][64];  // 8 KB

  const int b = blockIdx.x >> 8;
  const int pbase = (blockIdx.x & 255) * 16;
  const float* fb = feats + (size_t)b * NPTS * 6;
  const int wave = threadIdx.x >> 6;
  const int lane = threadIdx.x & 63;

  int ip[2];
  float xi[2], yi[2], zi[2], sqi[2], tau[2];
  u64 slot[2];
  int cnt[2];
#pragma unroll
  for (int p = 0; p < 2; ++p) {
    ip[p] = pbase + wave * 2 + p;
    const float* fr = fb + (size_t)ip[p] * 6;
    xi[p] = fr[0]; yi[p] = fr[1]; zi[p] = fr[2];
    sqi[p] = __fadd_rn(__fadd_rn(__fmul_rn(xi[p], xi[p]), __fmul_rn(yi[p], yi[p])),
                       __fmul_rn(zi[p], zi[p]));
    tau[p] = __uint_as_float(0x7f800000u);  // +inf: batch 0 all-pass bootstraps
    slot[p] = ~0ull;
    cnt[p] = 0;
  }

  // LDS rank-select merge of {<=48 buffered} U {16 slots} (verified R1/R2/R5).
  auto flush = [&](int p, bool fin) {
    u64* wb = &sbuf[wave][p][0];
    if (lane >= cnt[p] && lane < CAP) wb[lane] = ~0ull;  // clear unused
    if (lane < KNN) wb[CAP + lane] = slot[p];            // stage slots
    u64 myk = wb[lane];
    if ((u32)myk == (u32)ip[p]) {  // neutralize self
      myk = ~0ull;
      wb[lane] = ~0ull;
    }
    int rank = 0;
#pragma unroll
    for (int m = 0; m < 64; m += 4) {
      u64 k0 = wb[m], k1 = wb[m + 1], k2 = wb[m + 2], k3 = wb[m + 3];
      rank += (int)(k0 < myk) + (int)(k1 < myk) + (int)(k2 < myk) + (int)(k3 < myk);
    }
    if (fin) {
      if (rank < KNN)
        nbr[((size_t)(b * NPTS) + ip[p]) * KNN + rank] = (int)(u32)myk;
    } else {
      if (rank < KNN) wb[rank] = myk;
      u64 s15 = wb[15];
      if (lane < KNN) slot[p] = wb[lane];
      tau[p] = unmapmono((u32)(s15 >> 32));
    }
    cnt[p] = 0;
  };

  for (int tb = 0; tb < NPTS; tb += TS) {
    __syncthreads();  // prev tile readers done
    for (int t = threadIdx.x; t < TS; t += 512) {
      const float* fr = fb + (size_t)(tb + t) * 6;
      const float x = fr[0], y = fr[1], z = fr[2];
      // sq with the EXACT rn op sequence used for sqi (d2 bit-compat)
      const float sq = __fadd_rn(__fadd_rn(__fmul_rn(x, x), __fmul_rn(y, y)),
                                 __fmul_rn(z, z));
      float4 c; c.x = x; c.y = y; c.z = z; c.w = sq;
      sc[t] = c;
    }
    __syncthreads();

    for (int jb0 = 0; jb0 < TS; jb0 += 64) {
      const int tl = jb0 + lane;
      const int j = tb + tl;
      const float4 c = sc[tl];
      const v2f cx2 = {c.x, c.x}, cy2 = {c.y, c.y}, cz2 = {c.z, c.z},
                sq2 = {c.w, c.w};
      v2f X = {xi[0], xi[1]};
      v2f Y = {yi[0], yi[1]};
      v2f Z = {zi[0], zi[1]};
      v2f SQ = {sqi[0], sqi[1]};
      v2f dot = X * cx2;
      dot = __builtin_elementwise_fma(Y, cy2, dot);
      dot = __builtin_elementwise_fma(Z, cz2, dot);
      v2f two = {2.0f, 2.0f};
      v2f d2v = (SQ + sq2) - two * dot;  // contract(off): rn each op
      float d2s[2] = {d2v.x, d2v.y};
#pragma unroll
      for (int p = 0; p < 2; ++p) {
        const bool pred = d2s[p] <= tau[p];
        const u64 bal = __ballot(pred);
        if (bal) {
          const int npass = __popcll(bal);
          if (cnt[p] + npass > CAP) flush(p, false);
          const int pos = cnt[p] + (int)__builtin_amdgcn_mbcnt_hi(
                                        (u32)(bal >> 32),
                                        __builtin_amdgcn_mbcnt_lo((u32)bal, 0));
          const u64 key = ((u64)mapmono(d2s[p]) << 32) | (u32)j;
          if (npass <= CAP) {
            if (pred) sbuf[wave][p][pos] = key;
            cnt[p] += npass;
          } else {  // npass in (48,64]: batch-0 bootstrap + pathological ties
            if (pred && pos < CAP) sbuf[wave][p][pos] = key;
            cnt[p] = CAP;
            flush(p, false);
            if (pred && pos >= CAP) sbuf[wave][p][pos - CAP] = key;
            cnt[p] = npass - CAP;
          }
        }
      }
    }
  }
#pragma unroll
  for (int p = 0; p < 2; ++p) flush(p, true);
}

// ---------------------------------------------------------------------------
// T1: x1 = relu(((feats + sum_nbr feats) @ W1) * inv_deg + b1).  64 pts/block.
// (R3/R5 tail verbatim — measured 96-98 us total; R4 reg-weight variant=144.)
// ---------------------------------------------------------------------------
__global__ __launch_bounds__(256) void enc1_kernel(const float* __restrict__ feats,
                                                   const int* __restrict__ nbr,
                                                   const float* __restrict__ W1,
                                                   const float* __restrict__ b1,
                                                   float* __restrict__ x1) {
  __shared__ float af[64][6];
  const int tid = threadIdx.x;
  const int n0 = blockIdx.x * 64;
  const int gb = n0 & ~(NPTS - 1);

  if (tid < 128) {
    const int p = tid >> 1, h = tid & 1;
    const int n = n0 + p;
    const int d0 = h * 3;
    const int* nb = nbr + (size_t)n * KNN;
    const float* fr = feats + (size_t)n * 6 + d0;
    float a0 = fr[0], a1 = fr[1], a2 = fr[2];
#pragma unroll
    for (int t = 0; t < KNN; ++t) {
      const float* fq = feats + (size_t)(gb + nb[t]) * 6 + d0;
      a0 += fq[0]; a1 += fq[1]; a2 += fq[2];
    }
    af[p][d0] = a0; af[p][d0 + 1] = a1; af[p][d0 + 2] = a2;
  }
  __syncthreads();

  const int c = tid & 63, pg = tid >> 6;
  float w[6];
#pragma unroll
  for (int k = 0; k < 6; ++k) w[k] = W1[k * 64 + c];
  const float bv = b1[c];
  for (int pi = 0; pi < 16; ++pi) {
    const int p = pg * 16 + pi;
    float s = 0.f;
#pragma unroll
    for (int k = 0; k < 6; ++k) s = fmaf(af[p][k], w[k], s);
    x1[(size_t)(n0 + p) * 64 + c] = fmaxf(fmaf(s, INV_DEG, bv), 0.f);
  }
}

// ---------------------------------------------------------------------------
// T2: x2 = relu(((x1 + sum_nbr x1) @ W2) * inv_deg + b2).  16 pts/block.
// ---------------------------------------------------------------------------
__global__ __launch_bounds__(256) void enc2_kernel(const float* __restrict__ x1,
                                                   const int* __restrict__ nbr,
                                                   const float* __restrict__ W2,
                                                   const float* __restrict__ b2,
                                                   float* __restrict__ x2) {
  __shared__ float a1s[16][64];  // 4 KB
  __shared__ v2f w2s[64][64];    // 32 KB
  const int tid = threadIdx.x;
  const int n0 = blockIdx.x * 16;
  const int gb = n0 & ~(NPTS - 1);

#pragma unroll
  for (int i = 0; i < 16; ++i) {
    const int e = tid + 256 * i;
    const int k = e >> 6, l = e & 63;
    v2f w;
    w.x = W2[k * 128 + l];
    w.y = W2[k * 128 + 64 + l];
    w2s[k][l] = w;
  }
  {
    const int p = tid >> 4, c4 = tid & 15;
    const int n = n0 + p;
    const int* nb = nbr + (size_t)n * KNN;
    float4 s = ((const float4*)(x1 + (size_t)n * 64))[c4];
#pragma unroll
    for (int t = 0; t < KNN; ++t) {
      float4 v = ((const float4*)(x1 + (size_t)(gb + nb[t]) * 64))[c4];
      s.x += v.x; s.y += v.y; s.z += v.z; s.w += v.w;
    }
    *((float4*)&a1s[p][c4 * 4]) = s;
  }
  __syncthreads();

  const int wave = tid >> 6, lane = tid & 63;
  const int p0 = wave * 4;
  const float bx = b2[lane], by = b2[lane + 64];
  v2f acc0 = {0, 0}, acc1 = {0, 0}, acc2 = {0, 0}, acc3 = {0, 0};
  for (int k = 0; k < 64; k += 4) {
    const float4 a0 = *(const float4*)&a1s[p0 + 0][k];
    const float4 a1v = *(const float4*)&a1s[p0 + 1][k];
    const float4 a2v = *(const float4*)&a1s[p0 + 2][k];
    const float4 a3v = *(const float4*)&a1s[p0 + 3][k];
#pragma unroll
    for (int kk = 0; kk < 4; ++kk) {
      const v2f w = w2s[k + kk][lane];
      const float e0 = kk == 0 ? a0.x : kk == 1 ? a0.y : kk == 2 ? a0.z : a0.w;
      const float e1 = kk == 0 ? a1v.x : kk == 1 ? a1v.y : kk == 2 ? a1v.z : a1v.w;
      const float e2 = kk == 0 ? a2v.x : kk == 1 ? a2v.y : kk == 2 ? a2v.z : a2v.w;
      const float e3 = kk == 0 ? a3v.x : kk == 1 ? a3v.y : kk == 2 ? a3v.z : a3v.w;
      v2f v0 = {e0, e0}, v1 = {e1, e1}, v2 = {e2, e2}, v3 = {e3, e3};
      acc0 = __builtin_elementwise_fma(v0, w, acc0);
      acc1 = __builtin_elementwise_fma(v1, w, acc1);
      acc2 = __builtin_elementwise_fma(v2, w, acc2);
      acc3 = __builtin_elementwise_fma(v3, w, acc3);
    }
  }
  v2f accs[4] = {acc0, acc1, acc2, acc3};
#pragma unroll
  for (int pi = 0; pi < 4; ++pi) {
    float* row = x2 + (size_t)(n0 + p0 + pi) * 128;
    row[lane] = fmaxf(fmaf(accs[pi].x, INV_DEG, bx), 0.f);
    row[lane + 64] = fmaxf(fmaf(accs[pi].y, INV_DEG, by), 0.f);
  }
}

// ---------------------------------------------------------------------------
// T3: out = x2 @ Wf + bf (K=128). Split-K wave pairs, Wf in VGPRs, LDS
// combine (in-place safe on d_out).
// ---------------------------------------------------------------------------
__global__ __launch_bounds__(256) void enc3_kernel(const float* __restrict__ x2,
                                                   const float* __restrict__ Wf,
                                                   const float* __restrict__ bf,
                                                   float* __restrict__ out) {
  __shared__ float xs[16 * 128];      // 8 KB
  __shared__ float part[2][16][128];  // 16 KB
  const int tid = threadIdx.x;
  const int n0 = blockIdx.x * 16;

#pragma unroll
  for (int i = 0; i < 2; ++i) {
    const int e = tid + 256 * i;
    ((float4*)xs)[e] = ((const float4*)(x2 + (size_t)n0 * 128))[e];
  }

  const int wave = tid >> 6, lane = tid & 63;
  const int kh = wave & 1, pg = wave >> 1;
  v2f w[64];
#pragma unroll
  for (int j = 0; j < 64; ++j) {
    const int k = kh * 64 + j;
    w[j].x = Wf[k * 128 + lane];
    w[j].y = Wf[k * 128 + 64 + lane];
  }
  __syncthreads();

  for (int pi = 0; pi < 8; ++pi) {
    const int p = pg * 8 + pi;
    v2f acc = {0, 0};
    for (int j = 0; j < 64; j += 4) {
      const float4 a = *(const float4*)&xs[p * 128 + kh * 64 + j];
#pragma unroll
      for (int jj = 0; jj < 4; ++jj) {
        const float e = jj == 0 ? a.x : jj == 1 ? a.y : jj == 2 ? a.z : a.w;
        v2f v = {e, e};
        acc = __builtin_elementwise_fma(v, w[j + jj], acc);
      }
    }
    part[kh][p][lane] = acc.x;
    part[kh][p][lane + 64] = acc.y;
  }
  __syncthreads();

#pragma unroll
  for (int i = 0; i < 8; ++i) {
    const int e = tid + 256 * i;
    const int p = e >> 7, c = e & 127;
    out[(size_t)(n0 + p) * 128 + c] = part[0][p][c] + part[1][p][c] + bf[c];
  }
}

// ---------------------------------------------------------------------------
// Workspace: nbr@0 (2MB), x1@2MB (8MB). x2 lives in d_out (enc3 in-place).
// ---------------------------------------------------------------------------
extern "C" void kernel_launch(void* const* d_in, const int* in_sizes, int n_in,
                              void* d_out, int out_size, void* d_ws, size_t ws_size,
                              hipStream_t stream) {
  const float* feats = (const float*)d_in[0];
  const float* W1 = (const float*)d_in[1];
  const float* b1 = (const float*)d_in[2];
  const float* W2 = (const float*)d_in[3];
  const float* b2 = (const float*)d_in[4];
  const float* Wf = (const float*)d_in[5];
  const float* bf = (const float*)d_in[6];
  float* out = (float*)d_out;

  char* ws = (char*)d_ws;
  int* nbr = (int*)ws;
  float* x1 = (float*)(ws + (size_t)(2 << 20));
  float* x2 = out;

  knn_kernel<<<2048, 512, 0, stream>>>(feats, nbr);
  enc1_kernel<<<512, 256, 0, stream>>>(feats, nbr, W1, b1, x1);
  enc2_kernel<<<2048, 256, 0, stream>>>(x1, nbr, W2, b2, x2);
  enc3_kernel<<<2048, 256, 0, stream>>>(x2, Wf, bf, out);
}

// Round 9
// 232.404 us; speedup vs baseline: 1.3866x; 1.0052x over previous
//
#include <hip/hip_runtime.h>
#include <cstdint>
#include <cstddef>

#define NPTS 4096
#define KNN  16
#define INV_DEG (1.0f / 17.0f)
#define CAP  48   // knn per-point candidate buffer (entries [48..64) = slot staging)
#define TS   512  // candidate tile (float4 x/y/z/sq = 8 KB)

typedef unsigned long long u64;
typedef unsigned int u32;
typedef float v2f __attribute__((ext_vector_type(2)));

// raw sentinel {d2=+inf, j=0xFFFFFFFF}: converts above any real candidate
#define RAWSENT 0x7F800000FFFFFFFFull

__device__ __forceinline__ float unmapmono(u32 m) {
  u32 u = (m & 0x80000000u) ? (m ^ 0x80000000u) : ~m;
  return __uint_as_float(u);
}

// ---------------------------------------------------------------------------
// K1: exact KNN (top-16 smallest d2, tie -> lower index) + fused enc1.
// Ledger: (R3) no min-waves hint -> 45MB scratch spill; (R4) flush = LDS
// rank-select, NOT shfl bitonic; (R5) >16KB blocks lose residency; (R6) 16KB
// -> 72% occ; (R7/R8 FAIL) enc3 grid covered only half the points — identical
// absmax across rounds = deterministic coverage bug, not a race.
// ---------------------------------------------------------------------------
__global__ __launch_bounds__(512) void knn_kernel(const float* __restrict__ feats,
                                                  const float* __restrict__ W1,
                                                  const float* __restrict__ b1,
                                                  int* __restrict__ nbr,
                                                  float* __restrict__ x1) {
#pragma clang fp contract(off)
  __shared__ float4 sc[TS];       // 8 KB: {x, y, z, sq}
  __shared__ u64 sbuf[8][2][64];  // 8 KB

  const int b = blockIdx.x >> 8;
  const int pbase = (blockIdx.x & 255) * 16;
  const float* fb = feats + (size_t)b * NPTS * 6;
  const int wave = threadIdx.x >> 6;
  const int lane = threadIdx.x & 63;

  int ip[2];
  float xi[2], yi[2], zi[2], sqi[2], tau[2];
  u64 slot[2];
  int cnt[2];
#pragma unroll
  for (int p = 0; p < 2; ++p) {
    ip[p] = pbase + wave * 2 + p;
    const float* fr = fb + (size_t)ip[p] * 6;
    xi[p] = fr[0]; yi[p] = fr[1]; zi[p] = fr[2];
    sqi[p] = __fadd_rn(__fadd_rn(__fmul_rn(xi[p], xi[p]), __fmul_rn(yi[p], yi[p])),
                       __fmul_rn(zi[p], zi[p]));
    tau[p] = __uint_as_float(0x7f800000u);  // +inf: batch 0 all-pass bootstraps
    slot[p] = ~0ull;
    cnt[p] = 0;
  }

  // LDS rank-select merge of {<=48 raw buffered} U {16 mono slots}.
  auto flush = [&](int p) {
    u64* wb = &sbuf[wave][p][0];
    if (lane >= cnt[p] && lane < CAP) wb[lane] = RAWSENT;  // clear unused (raw)
    if (lane < KNN) wb[CAP + lane] = slot[p];              // stage slots (mono)
    u64 myk = wb[lane];
    if (lane < CAP) {  // raw -> mono; neutralize self
      u32 hi = (u32)(myk >> 32);
      hi ^= ((u32)((int)hi >> 31) | 0x80000000u);
      myk = ((u64)hi << 32) | (u32)myk;
      if ((u32)myk == (u32)ip[p]) myk = ~0ull;
      wb[lane] = myk;
    }
    int rank = 0;
#pragma unroll
    for (int m = 0; m < 64; m += 4) {
      u64 k0 = wb[m], k1 = wb[m + 1], k2 = wb[m + 2], k3 = wb[m + 3];
      rank += (int)(k0 < myk) + (int)(k1 < myk) + (int)(k2 < myk) + (int)(k3 < myk);
    }
    if (rank < KNN) wb[rank] = myk;
    u64 s15 = wb[15];
    if (lane < KNN) slot[p] = wb[lane];
    tau[p] = unmapmono((u32)(s15 >> 32));
    cnt[p] = 0;
  };

  for (int tb = 0; tb < NPTS; tb += TS) {
    __syncthreads();  // prev tile readers done
    for (int t = threadIdx.x; t < TS; t += 512) {
      const float* fr = fb + (size_t)(tb + t) * 6;
      const float x = fr[0], y = fr[1], z = fr[2];
      // sq with the EXACT rn op sequence used for sqi (d2 bit-compat)
      const float sq = __fadd_rn(__fadd_rn(__fmul_rn(x, x), __fmul_rn(y, y)),
                                 __fmul_rn(z, z));
      float4 c; c.x = x; c.y = y; c.z = z; c.w = sq;
      sc[t] = c;
    }
    __syncthreads();

    for (int jb0 = 0; jb0 < TS; jb0 += 64) {
      const int tl = jb0 + lane;
      const int j = tb + tl;
      const float4 c = sc[tl];
      const v2f cx2 = {c.x, c.x}, cy2 = {c.y, c.y}, cz2 = {c.z, c.z},
                sq2 = {c.w, c.w};
      v2f X = {xi[0], xi[1]};
      v2f Y = {yi[0], yi[1]};
      v2f Z = {zi[0], zi[1]};
      v2f SQ = {sqi[0], sqi[1]};
      v2f dot = X * cx2;
      dot = __builtin_elementwise_fma(Y, cy2, dot);
      dot = __builtin_elementwise_fma(Z, cz2, dot);
      v2f two = {2.0f, 2.0f};
      v2f d2v = (SQ + sq2) - two * dot;  // contract(off): rn each op
      float d2s[2] = {d2v.x, d2v.y};
#pragma unroll
      for (int p = 0; p < 2; ++p) {
        const bool pred = d2s[p] <= tau[p];
        const u64 bal = __ballot(pred);
        if (bal) {
          const int npass = __popcll(bal);
          if (cnt[p] + npass > CAP) flush(p);
          const int pos = cnt[p] + (int)__builtin_amdgcn_mbcnt_hi(
                                        (u32)(bal >> 32),
                                        __builtin_amdgcn_mbcnt_lo((u32)bal, 0));
          const u64 key = ((u64)__float_as_uint(d2s[p]) << 32) | (u32)j;  // RAW
          if (npass <= CAP) {
            if (pred) sbuf[wave][p][pos] = key;
            cnt[p] += npass;
          } else {  // npass in (48,64]: batch-0 bootstrap + pathological ties
            if (pred && pos < CAP) sbuf[wave][p][pos] = key;
            cnt[p] = CAP;
            flush(p);
            if (pred && pos >= CAP) sbuf[wave][p][pos - CAP] = key;
            cnt[p] = npass - CAP;
          }
        }
      }
    }
  }
#pragma unroll
  for (int p = 0; p < 2; ++p) flush(p);  // final merge -> slots hold winners

  // ---- fused enc1: x1[n] = relu(((Σ_{nbr ∪ self} feats) @ W1)*inv_deg + b1)
  // Neighbor indices taken DIRECTLY from slot[] registers (no nbr read-back).
  float* fsc = (float*)&sbuf[wave][0][0];  // wave-private scratch (432 B)
  float w1r[6];
#pragma unroll
  for (int k = 0; k < 6; ++k) w1r[k] = W1[k * 64 + lane];
  const float b1r = b1[lane];

#pragma unroll
  for (int p = 0; p < 2; ++p) {
    const int n = b * NPTS + ip[p];
    const int row = (lane < KNN) ? (int)(u32)slot[p] : ip[p];
    if (lane < KNN)
      nbr[(size_t)n * KNN + lane] = row;  // for enc2's gather
    if (lane < 17) {
      const float* fr = fb + (size_t)row * 6;
      float2 r0 = *(const float2*)(fr);
      float2 r1 = *(const float2*)(fr + 2);
      float2 r2 = *(const float2*)(fr + 4);
      fsc[lane * 6 + 0] = r0.x; fsc[lane * 6 + 1] = r0.y;
      fsc[lane * 6 + 2] = r1.x; fsc[lane * 6 + 3] = r1.y;
      fsc[lane * 6 + 4] = r2.x; fsc[lane * 6 + 5] = r2.y;
    }
    __syncthreads();  // all waves execute both iterations: barriers match
    if (lane < 6) {
      float s = 0.f;
#pragma unroll
      for (int t = 0; t < 17; ++t) s += fsc[t * 6 + lane];
      fsc[102 + lane] = s;
    }
    __syncthreads();
    float s = 0.f;
#pragma unroll
    for (int k = 0; k < 6; ++k) s = fmaf(fsc[102 + k], w1r[k], s);
    x1[(size_t)n * 64 + lane] = fmaxf(fmaf(s, INV_DEG, b1r), 0.f);
    __syncthreads();  // protect fsc reuse for p=1
  }
}

// ---------------------------------------------------------------------------
// T2: x2 = relu(((x1 + sum_nbr x1) @ W2) * inv_deg + b2).  32 pts/block,
// grid 1024 (32768 points total).
// ---------------------------------------------------------------------------
__global__ __launch_bounds__(256) void enc2_kernel(const float* __restrict__ x1,
                                                   const int* __restrict__ nbr,
                                                   const float* __restrict__ W2,
                                                   const float* __restrict__ b2,
                                                   float* __restrict__ x2) {
  __shared__ float a1s[32][64];  // 8 KB
  __shared__ v2f w2s[64][64];    // 32 KB
  const int tid = threadIdx.x;
  const int n0 = blockIdx.x * 32;
  const int gb = n0 & ~(NPTS - 1);

#pragma unroll
  for (int i = 0; i < 16; ++i) {
    const int e = tid + 256 * i;
    const int k = e >> 6, l = e & 63;
    v2f w;
    w.x = W2[k * 128 + l];
    w.y = W2[k * 128 + 64 + l];
    w2s[k][l] = w;
  }
#pragma unroll
  for (int r = 0; r < 2; ++r) {
    const int p = r * 16 + (tid >> 4), c4 = tid & 15;
    const int n = n0 + p;
    const int* nb = nbr + (size_t)n * KNN;
    float4 s = ((const float4*)(x1 + (size_t)n * 64))[c4];
#pragma unroll
    for (int t = 0; t < KNN; ++t) {
      float4 v = ((const float4*)(x1 + (size_t)(gb + nb[t]) * 64))[c4];
      s.x += v.x; s.y += v.y; s.z += v.z; s.w += v.w;
    }
    *((float4*)&a1s[p][c4 * 4]) = s;
  }
  __syncthreads();

  const int wave = tid >> 6, lane = tid & 63;
  const int p0 = wave * 8;
  const float bx = b2[lane], by = b2[lane + 64];
  v2f acc[8];
#pragma unroll
  for (int i = 0; i < 8; ++i) acc[i] = (v2f){0, 0};
  for (int k = 0; k < 64; k += 4) {
    float4 a[8];
#pragma unroll
    for (int i = 0; i < 8; ++i) a[i] = *(const float4*)&a1s[p0 + i][k];
#pragma unroll
    for (int kk = 0; kk < 4; ++kk) {
      const v2f w = w2s[k + kk][lane];
#pragma unroll
      for (int i = 0; i < 8; ++i) {
        const float e = kk == 0 ? a[i].x : kk == 1 ? a[i].y : kk == 2 ? a[i].z
                                                                      : a[i].w;
        v2f v = {e, e};
        acc[i] = __builtin_elementwise_fma(v, w, acc[i]);
      }
    }
  }
#pragma unroll
  for (int pi = 0; pi < 8; ++pi) {
    float* row = x2 + (size_t)(n0 + p0 + pi) * 128;
    row[lane] = fmaxf(fmaf(acc[pi].x, INV_DEG, bx), 0.f);
    row[lane + 64] = fmaxf(fmaf(acc[pi].y, INV_DEG, by), 0.f);
  }
}

// ---------------------------------------------------------------------------
// T3: out = x2 @ Wf + bf (K=128). Split-K wave pairs, Wf in VGPRs, LDS
// combine. 32 pts/block, grid 1024 (FIX R7/R8: 512 covered only half the
// points -> absmax 2.82 from memset-zero rows). In-place safe on d_out.
// ---------------------------------------------------------------------------
__global__ __launch_bounds__(256) void enc3_kernel(const float* __restrict__ x2,
                                                   const float* __restrict__ Wf,
                                                   const float* __restrict__ bf,
                                                   float* __restrict__ out) {
  __shared__ float xs[32 * 128];      // 16 KB
  __shared__ float part[2][32][128];  // 32 KB
  const int tid = threadIdx.x;
  const int n0 = blockIdx.x * 32;

#pragma unroll
  for (int i = 0; i < 4; ++i) {
    const int e = tid + 256 * i;
    ((float4*)xs)[e] = ((const float4*)(x2 + (size_t)n0 * 128))[e];
  }

  const int wave = tid >> 6, lane = tid & 63;
  const int kh = wave & 1, pg = wave >> 1;
  v2f w[64];
#pragma unroll
  for (int j = 0; j < 64; ++j) {
    const int k = kh * 64 + j;
    w[j].x = Wf[k * 128 + lane];
    w[j].y = Wf[k * 128 + 64 + lane];
  }
  __syncthreads();

  for (int pi = 0; pi < 16; ++pi) {
    const int p = pg * 16 + pi;
    v2f acc = {0, 0};
    for (int j = 0; j < 64; j += 4) {
      const float4 a = *(const float4*)&xs[p * 128 + kh * 64 + j];
#pragma unroll
      for (int jj = 0; jj < 4; ++jj) {
        const float e = jj == 0 ? a.x : jj == 1 ? a.y : jj == 2 ? a.z : a.w;
        v2f v = {e, e};
        acc = __builtin_elementwise_fma(v, w[j + jj], acc);
      }
    }
    part[kh][p][lane] = acc.x;
    part[kh][p][lane + 64] = acc.y;
  }
  __syncthreads();

#pragma unroll
  for (int i = 0; i < 16; ++i) {
    const int e = tid + 256 * i;  // 4096 outputs
    const int p = e >> 7, c = e & 127;
    out[(size_t)(n0 + p) * 128 + c] = part[0][p][c] + part[1][p][c] + bf[c];
  }
}

// ---------------------------------------------------------------------------
// Workspace: nbr@0 (2MB), x1@2MB (8MB). x2 lives in d_out (enc3 in-place).
// ---------------------------------------------------------------------------
extern "C" void kernel_launch(void* const* d_in, const int* in_sizes, int n_in,
                              void* d_out, int out_size, void* d_ws, size_t ws_size,
                              hipStream_t stream) {
  const float* feats = (const float*)d_in[0];
  const float* W1 = (const float*)d_in[1];
  const float* b1 = (const float*)d_in[2];
  const float* W2 = (const float*)d_in[3];
  const float* b2 = (const float*)d_in[4];
  const float* Wf = (const float*)d_in[5];
  const float* bf = (const float*)d_in[6];
  float* out = (float*)d_out;

  char* ws = (char*)d_ws;
  int* nbr = (int*)ws;
  float* x1 = (float*)(ws + (size_t)(2 << 20));
  float* x2 = out;

  knn_kernel<<<2048, 512, 0, stream>>>(feats, W1, b1, nbr, x1);
  enc2_kernel<<<1024, 256, 0, stream>>>(x1, nbr, W2, b2, x2);
  enc3_kernel<<<1024, 256, 0, stream>>>(x2, Wf, bf, out);
}